// Round 1
// baseline (362.818 us; speedup 1.0000x reference)
//
#include <hip/hip_runtime.h>
#include <hip/hip_bf16.h>

#define BSZ 8192
#define DIM 128

typedef __attribute__((ext_vector_type(8))) short bf16x8;
typedef __attribute__((ext_vector_type(4))) float f32x4;

__device__ __forceinline__ ushort f32_to_bf16(float f) {
    unsigned u = __float_as_uint(f);
    u += 0x7FFF + ((u >> 16) & 1);   // round-to-nearest-even
    return (ushort)(u >> 16);
}

// K1: per-row sum of squares (fp32) + bf16 conversion of x into workspace.
__global__ __launch_bounds__(256) void prep_kernel(const float* __restrict__ x,
                                                   ushort* __restrict__ xb,
                                                   float* __restrict__ sq) {
    const int wid  = threadIdx.x >> 6;
    const int lane = threadIdx.x & 63;
    const int row  = blockIdx.x * 4 + wid;
    const float2 v = *reinterpret_cast<const float2*>(x + (size_t)row * DIM + lane * 2);
    float s = v.x * v.x + v.y * v.y;
    #pragma unroll
    for (int off = 32; off; off >>= 1) s += __shfl_down(s, off);
    if (lane == 0) sq[row] = s;
    ushort2 b;
    b.x = f32_to_bf16(v.x);
    b.y = f32_to_bf16(v.y);
    *reinterpret_cast<ushort2*>(xb + (size_t)row * DIM + lane * 2) = b;
}

// PHASE 0: accumulate column sums of the RBF kernel (no matrix write).
// PHASE 1: recompute kernel values, normalize by rsqrt(colsum) on both axes, write out.
template <int PHASE>
__global__ __launch_bounds__(256) void rbf_kernel(const ushort* __restrict__ xb,
                                                  const float* __restrict__ sq,
                                                  float* __restrict__ colsum,
                                                  float* __restrict__ out) {
    const int lane = threadIdx.x & 63;
    const int wid  = threadIdx.x >> 6;
    const int fr   = lane & 15;   // fragment row/col within 16
    const int kg   = lane >> 4;   // k-group (0..3)

    const int bx = blockIdx.x & 63;
    const int by = blockIdx.x >> 6;
    const int row0 = by * 128 + (wid >> 1) * 64;  // wave's 64x64 sub-tile origin
    const int col0 = bx * 128 + (wid & 1) * 64;

    f32x4 acc[4][4];
    #pragma unroll
    for (int mi = 0; mi < 4; ++mi)
        #pragma unroll
        for (int ni = 0; ni < 4; ++ni)
            acc[mi][ni] = (f32x4){0.f, 0.f, 0.f, 0.f};

    #pragma unroll
    for (int kk = 0; kk < 4; ++kk) {
        const int ko = kk * 32 + kg * 8;
        bf16x8 a[4], b[4];
        #pragma unroll
        for (int mi = 0; mi < 4; ++mi)
            a[mi] = *reinterpret_cast<const bf16x8*>(xb + (size_t)(row0 + mi * 16 + fr) * DIM + ko);
        #pragma unroll
        for (int ni = 0; ni < 4; ++ni)
            b[ni] = *reinterpret_cast<const bf16x8*>(xb + (size_t)(col0 + ni * 16 + fr) * DIM + ko);
        #pragma unroll
        for (int mi = 0; mi < 4; ++mi)
            #pragma unroll
            for (int ni = 0; ni < 4; ++ni)
                acc[mi][ni] = __builtin_amdgcn_mfma_f32_16x16x32_bf16(a[mi], b[ni], acc[mi][ni], 0, 0, 0);
    }

    // Epilogue. C/D layout (m89-verified): col = lane&15, row = (lane>>4)*4 + reg.
    float sqr[4][4];
    #pragma unroll
    for (int mi = 0; mi < 4; ++mi) {
        const f32x4 t = *reinterpret_cast<const f32x4*>(sq + row0 + mi * 16 + kg * 4);
        #pragma unroll
        for (int r = 0; r < 4; ++r) sqr[mi][r] = t[r];
    }
    float sqc[4];
    #pragma unroll
    for (int ni = 0; ni < 4; ++ni) sqc[ni] = sq[col0 + ni * 16 + fr];

    const float inv = 1.0f / 512.0f;  // 1/(2*sigma^2)

    if (PHASE == 0) {
        float csum[4] = {0.f, 0.f, 0.f, 0.f};
        #pragma unroll
        for (int mi = 0; mi < 4; ++mi)
            #pragma unroll
            for (int ni = 0; ni < 4; ++ni)
                #pragma unroll
                for (int r = 0; r < 4; ++r) {
                    float t = fminf((2.f * acc[mi][ni][r] - sqr[mi][r] - sqc[ni]) * inv, 0.f);
                    csum[ni] += __expf(t);
                }
        // Reduce across the 4 lanes sharing the same column (bits 4,5 of lane).
        #pragma unroll
        for (int ni = 0; ni < 4; ++ni) {
            csum[ni] += __shfl_xor(csum[ni], 16);
            csum[ni] += __shfl_xor(csum[ni], 32);
        }
        if (lane < 16) {
            #pragma unroll
            for (int ni = 0; ni < 4; ++ni)
                atomicAdd(&colsum[col0 + ni * 16 + fr], csum[ni]);
        }
    } else {
        float dsc[4];
        #pragma unroll
        for (int ni = 0; ni < 4; ++ni) dsc[ni] = rsqrtf(colsum[col0 + ni * 16 + fr]);
        float dsr[4][4];
        #pragma unroll
        for (int mi = 0; mi < 4; ++mi) {
            const f32x4 t = *reinterpret_cast<const f32x4*>(colsum + row0 + mi * 16 + kg * 4);
            #pragma unroll
            for (int r = 0; r < 4; ++r) dsr[mi][r] = rsqrtf(t[r]);
        }
        #pragma unroll
        for (int mi = 0; mi < 4; ++mi)
            #pragma unroll
            for (int ni = 0; ni < 4; ++ni)
                #pragma unroll
                for (int r = 0; r < 4; ++r) {
                    float t = fminf((2.f * acc[mi][ni][r] - sqr[mi][r] - sqc[ni]) * inv, 0.f);
                    float k = __expf(t);
                    const int row = row0 + mi * 16 + kg * 4 + r;
                    const int col = col0 + ni * 16 + fr;
                    out[(size_t)row * BSZ + col] = k * dsr[mi][r] * dsc[ni];
                }
    }
}

extern "C" void kernel_launch(void* const* d_in, const int* in_sizes, int n_in,
                              void* d_out, int out_size, void* d_ws, size_t ws_size,
                              hipStream_t stream) {
    const float* x = (const float*)d_in[0];
    float* out = (float*)d_out;

    ushort* xb    = (ushort*)d_ws;                                  // 8192*128*2 = 2 MiB
    float* sq     = (float*)((char*)d_ws + (size_t)BSZ * DIM * 2);  // 32 KiB
    float* colsum = sq + BSZ;                                       // 32 KiB

    hipMemsetAsync(colsum, 0, BSZ * sizeof(float), stream);
    prep_kernel<<<BSZ / 4, 256, 0, stream>>>(x, xb, sq);
    rbf_kernel<0><<<64 * 64, 256, 0, stream>>>(xb, sq, colsum, out);
    rbf_kernel<1><<<64 * 64, 256, 0, stream>>>(xb, sq, colsum, out);
}

// Round 2
// 325.480 us; speedup vs baseline: 1.1147x; 1.1147x over previous
//
#include <hip/hip_runtime.h>
#include <hip/hip_bf16.h>

#define BSZ 8192
#define DIM 128

typedef __attribute__((ext_vector_type(8))) short bf16x8;
typedef __attribute__((ext_vector_type(4))) float f32x4;

__device__ __forceinline__ ushort f32_to_bf16(float f) {
    unsigned u = __float_as_uint(f);
    u += 0x7FFF + ((u >> 16) & 1);   // round-to-nearest-even
    return (ushort)(u >> 16);
}

// K1: per-row sum of squares (fp32) + bf16 conversion of x into a BLOCKED
// fragment layout: xb[((g*4 + kk)*64 + lane)*8 + e] = bf16(x[g*16 + (lane&15)]
// [kk*32 + (lane>>4)*8 + e]).  One MFMA fragment load = 64 lanes x 16 B
// contiguous = a single coalesced 1 KB transaction.
__global__ __launch_bounds__(256) void prep_kernel(const float* __restrict__ x,
                                                   ushort* __restrict__ xb,
                                                   float* __restrict__ sq) {
    const int wid  = threadIdx.x >> 6;
    const int lane = threadIdx.x & 63;
    const int g    = blockIdx.x * 4 + wid;   // 16-row group, 0..511
    const int fr   = lane & 15;
    const int kg   = lane >> 4;
    const int row  = g * 16 + fr;

    float s = 0.f;
    #pragma unroll
    for (int kk = 0; kk < 4; ++kk) {
        const float* p = x + (size_t)row * DIM + kk * 32 + kg * 8;
        const float4 v0 = *reinterpret_cast<const float4*>(p);
        const float4 v1 = *reinterpret_cast<const float4*>(p + 4);
        s += v0.x * v0.x + v0.y * v0.y + v0.z * v0.z + v0.w * v0.w;
        s += v1.x * v1.x + v1.y * v1.y + v1.z * v1.z + v1.w * v1.w;
        bf16x8 b;
        b[0] = (short)f32_to_bf16(v0.x); b[1] = (short)f32_to_bf16(v0.y);
        b[2] = (short)f32_to_bf16(v0.z); b[3] = (short)f32_to_bf16(v0.w);
        b[4] = (short)f32_to_bf16(v1.x); b[5] = (short)f32_to_bf16(v1.y);
        b[6] = (short)f32_to_bf16(v1.z); b[7] = (short)f32_to_bf16(v1.w);
        *reinterpret_cast<bf16x8*>(xb + ((size_t)(g * 4 + kk) * 64 + lane) * 8) = b;
    }
    // row sum-of-squares: each lane holds the partial over its kg's 32 cols
    s += __shfl_xor(s, 16);
    s += __shfl_xor(s, 32);
    if (lane < 16) sq[row] = s;
}

// PHASE 0: accumulate column sums of the RBF kernel (no matrix write).
// PHASE 1: recompute kernel values, normalize by rsqrt(colsum) both axes, write.
template <int PHASE>
__global__ __launch_bounds__(256) void rbf_kernel(const ushort* __restrict__ xb,
                                                  const float* __restrict__ sq,
                                                  float* __restrict__ colsum,
                                                  float* __restrict__ out) {
    const int lane = threadIdx.x & 63;
    const int wid  = threadIdx.x >> 6;
    const int fr   = lane & 15;   // fragment row/col within 16
    const int kg   = lane >> 4;   // k-group (0..3)

    const int bx = blockIdx.x & 63;
    const int by = blockIdx.x >> 6;
    const int row0 = by * 128 + (wid >> 1) * 64;  // wave's 64x64 sub-tile origin
    const int col0 = bx * 128 + (wid & 1) * 64;
    const int ga = row0 >> 4;   // 16-row group index for A fragments
    const int gb = col0 >> 4;   // 16-row group index for B fragments

    f32x4 acc[4][4];
    #pragma unroll
    for (int mi = 0; mi < 4; ++mi)
        #pragma unroll
        for (int ni = 0; ni < 4; ++ni)
            acc[mi][ni] = (f32x4){0.f, 0.f, 0.f, 0.f};

    #pragma unroll
    for (int kk = 0; kk < 4; ++kk) {
        bf16x8 a[4], b[4];
        #pragma unroll
        for (int mi = 0; mi < 4; ++mi)
            a[mi] = *reinterpret_cast<const bf16x8*>(
                xb + ((size_t)((ga + mi) * 4 + kk) * 64 + lane) * 8);
        #pragma unroll
        for (int ni = 0; ni < 4; ++ni)
            b[ni] = *reinterpret_cast<const bf16x8*>(
                xb + ((size_t)((gb + ni) * 4 + kk) * 64 + lane) * 8);
        #pragma unroll
        for (int mi = 0; mi < 4; ++mi)
            #pragma unroll
            for (int ni = 0; ni < 4; ++ni)
                acc[mi][ni] = __builtin_amdgcn_mfma_f32_16x16x32_bf16(a[mi], b[ni], acc[mi][ni], 0, 0, 0);
    }

    // Epilogue. C/D layout (m89-verified): col = lane&15, row = (lane>>4)*4 + reg.
    float sqr[4][4];
    #pragma unroll
    for (int mi = 0; mi < 4; ++mi) {
        const f32x4 t = *reinterpret_cast<const f32x4*>(sq + row0 + mi * 16 + kg * 4);
        #pragma unroll
        for (int r = 0; r < 4; ++r) sqr[mi][r] = t[r];
    }
    float sqc[4];
    #pragma unroll
    for (int ni = 0; ni < 4; ++ni) sqc[ni] = sq[col0 + ni * 16 + fr];

    const float inv = 1.0f / 512.0f;  // 1/(2*sigma^2)

    if (PHASE == 0) {
        float csum[4] = {0.f, 0.f, 0.f, 0.f};
        #pragma unroll
        for (int mi = 0; mi < 4; ++mi)
            #pragma unroll
            for (int ni = 0; ni < 4; ++ni)
                #pragma unroll
                for (int r = 0; r < 4; ++r) {
                    float t = fminf((2.f * acc[mi][ni][r] - sqr[mi][r] - sqc[ni]) * inv, 0.f);
                    csum[ni] += __expf(t);
                }
        // Reduce across the 4 lanes sharing the same column (bits 4,5 of lane).
        #pragma unroll
        for (int ni = 0; ni < 4; ++ni) {
            csum[ni] += __shfl_xor(csum[ni], 16);
            csum[ni] += __shfl_xor(csum[ni], 32);
        }
        if (lane < 16) {
            #pragma unroll
            for (int ni = 0; ni < 4; ++ni)
                atomicAdd(&colsum[col0 + ni * 16 + fr], csum[ni]);
        }
    } else {
        float dsc[4];
        #pragma unroll
        for (int ni = 0; ni < 4; ++ni) dsc[ni] = rsqrtf(colsum[col0 + ni * 16 + fr]);
        float dsr[4][4];
        #pragma unroll
        for (int mi = 0; mi < 4; ++mi) {
            const f32x4 t = *reinterpret_cast<const f32x4*>(colsum + row0 + mi * 16 + kg * 4);
            #pragma unroll
            for (int r = 0; r < 4; ++r) dsr[mi][r] = rsqrtf(t[r]);
        }
        #pragma unroll
        for (int mi = 0; mi < 4; ++mi)
            #pragma unroll
            for (int ni = 0; ni < 4; ++ni)
                #pragma unroll
                for (int r = 0; r < 4; ++r) {
                    float t = fminf((2.f * acc[mi][ni][r] - sqr[mi][r] - sqc[ni]) * inv, 0.f);
                    float k = __expf(t);
                    const int row = row0 + mi * 16 + kg * 4 + r;
                    const int col = col0 + ni * 16 + fr;
                    // streaming store: don't evict L2-resident xb
                    __builtin_nontemporal_store(k * dsr[mi][r] * dsc[ni],
                                                &out[(size_t)row * BSZ + col]);
                }
    }
}

extern "C" void kernel_launch(void* const* d_in, const int* in_sizes, int n_in,
                              void* d_out, int out_size, void* d_ws, size_t ws_size,
                              hipStream_t stream) {
    const float* x = (const float*)d_in[0];
    float* out = (float*)d_out;

    ushort* xb    = (ushort*)d_ws;                                  // 8192*128*2 = 2 MiB (blocked layout)
    float* sq     = (float*)((char*)d_ws + (size_t)BSZ * DIM * 2);  // 32 KiB
    float* colsum = sq + BSZ;                                       // 32 KiB

    hipMemsetAsync(colsum, 0, BSZ * sizeof(float), stream);
    prep_kernel<<<512 / 4, 256, 0, stream>>>(x, xb, sq);
    rbf_kernel<0><<<64 * 64, 256, 0, stream>>>(xb, sq, colsum, out);
    rbf_kernel<1><<<64 * 64, 256, 0, stream>>>(xb, sq, colsum, out);
}